// Round 1
// baseline (190.136 us; speedup 1.0000x reference)
//
#include <hip/hip_runtime.h>

// Problem constants (fixed by the reference file)
#define BATCH 2048
#define MM    256
#define DD    1024

// Main-kernel tiling
#define BB 128          // batches per block
#define BM 64           // mixture components per block
#define SD 16           // d-splits (grid.z)
#define DC (DD / SD)    // 64 d per block
#define KC 16           // d per LDS stage
#define TB 8            // per-thread batch tile
#define TM 4            // per-thread m tile
#define LXS (BB + 4)    // padded LDS row stride (words), 132*4B % 16 == 0
#define LRS (BM + 4)    // 68*4B % 16 == 0

#define LOG2E 1.4426950408889634f
#define LN2   0.6931471805599453f

// ws layout (floats): [comp2: BATCH*MM][rbuf: MM*DD][cst: MM]
#define WS_COMP 0
#define WS_R    ((size_t)BATCH * MM)
#define WS_CST  (WS_R + (size_t)MM * DD)

// ---- exact log2 bookkeeping via frexp (full-rate VALU, no transcendental) ----
__device__ __forceinline__ float fr_mant(float x) {
#if __has_builtin(__builtin_amdgcn_frexp_mantf)
    return __builtin_amdgcn_frexp_mantf(x);
#else
    unsigned u = __float_as_uint(x);
    return __uint_as_float((u & 0x807FFFFFu) | 0x3F000000u);  // mant in [0.5,1)
#endif
}
__device__ __forceinline__ int fr_exp(float x) {
#if __has_builtin(__builtin_amdgcn_frexp_expf)
    return __builtin_amdgcn_frexp_expf(x);
#else
    return (int)((__float_as_uint(x) >> 23) & 0xFFu) - 126;
#endif
}

// ---------------------------------------------------------------------------
// Kernel A: precompute r[m][d] = e^z - 1  (so lik = q*(1 + x*r), q = 1-p)
// and cst[m] = sum_d log2(q[m][d]) + log2(softmax(W)[m])
// One block per m; W-logsumexp recomputed redundantly per block (cheap).
// ---------------------------------------------------------------------------
__global__ __launch_bounds__(256) void precomp_kernel(
        const float* __restrict__ P, const float* __restrict__ Wv,
        float* __restrict__ rbuf, float* __restrict__ cst) {
    const int m = blockIdx.x;
    const int t = threadIdx.x;
    const int lane = t & 63, wid = t >> 6;

    float4 z = ((const float4*)(P + (size_t)m * DD))[t];
    float e0 = __expf(z.x), e1 = __expf(z.y), e2 = __expf(z.z), e3 = __expf(z.w);
    ((float4*)(rbuf + (size_t)m * DD))[t] =
        make_float4(e0 - 1.f, e1 - 1.f, e2 - 1.f, e3 - 1.f);
    // log2(q) = -log2(1 + e^z)
    float part = -(__log2f(1.f + e0) + __log2f(1.f + e1) +
                   __log2f(1.f + e2) + __log2f(1.f + e3));

    __shared__ float smA[4], smB[4];

    #pragma unroll
    for (int o = 32; o; o >>= 1) part += __shfl_xor(part, o);
    if (lane == 0) smA[wid] = part;

    float w = Wv[t];   // blockDim == MM == 256
    float mx = w;
    #pragma unroll
    for (int o = 32; o; o >>= 1) mx = fmaxf(mx, __shfl_xor(mx, o));
    if (lane == 0) smB[wid] = mx;
    __syncthreads();

    float rowc = smA[0] + smA[1] + smA[2] + smA[3];
    float gmx  = fmaxf(fmaxf(smB[0], smB[1]), fmaxf(smB[2], smB[3]));

    float se = __expf(w - gmx);
    #pragma unroll
    for (int o = 32; o; o >>= 1) se += __shfl_xor(se, o);
    __syncthreads();
    if (lane == 0) smA[wid] = se;
    __syncthreads();

    if (t == 0) {
        float sum = smA[0] + smA[1] + smA[2] + smA[3];
        // cst = sum_d log2 q + (W[m]-lse)*log2e  (all in log2 units)
        cst[m] = rowc + (Wv[m] - gmx) * LOG2E - __log2f(sum);
    }
}

// ---------------------------------------------------------------------------
// Kernel B: comp2[b][m] += sum_{d in split} log2(1 + x[b][d]*r[m][d])
// Register tile TB x TM per thread; products of 8 closed via frexp.
// ---------------------------------------------------------------------------
__global__ __launch_bounds__(256, 4) void main_kernel(
        const float* __restrict__ x, const float* __restrict__ rbuf,
        float* __restrict__ comp2) {
    __shared__ __align__(16) float lx[KC * LXS];
    __shared__ __align__(16) float lr[KC * LRS];

    const int tid = threadIdx.x;
    const int tx = tid & 15;    // m direction (16 * TM = 64)
    const int ty = tid >> 4;    // batch direction (16 * TB = 128)
    const int m0 = blockIdx.x * BM;
    const int b0 = blockIdx.y * BB;
    const int d0 = blockIdx.z * DC;

    float prod[TB][TM];
    int   acce[TB][TM];
    #pragma unroll
    for (int i = 0; i < TB; ++i)
        #pragma unroll
        for (int j = 0; j < TM; ++j) { prod[i][j] = 1.0f; acce[i][j] = 0; }

    for (int c = 0; c < DC / KC; ++c) {
        const int dc = d0 + c * KC;
        __syncthreads();
        // stage x tile [KC][BB] transposed: 128 rows x 4 float4-segs
        #pragma unroll
        for (int l = 0; l < 2; ++l) {
            int idx = tid + 256 * l;
            int row = idx >> 2;          // 0..127
            int seg = idx & 3;           // 0..3
            float4 v = *(const float4*)(x + (size_t)(b0 + row) * DD + dc + seg * 4);
            lx[(seg * 4 + 0) * LXS + row] = v.x;
            lx[(seg * 4 + 1) * LXS + row] = v.y;
            lx[(seg * 4 + 2) * LXS + row] = v.z;
            lx[(seg * 4 + 3) * LXS + row] = v.w;
        }
        // stage r tile [KC][BM] transposed: 64 rows x 4 float4-segs
        {
            int row = tid >> 2;          // 0..63
            int seg = tid & 3;
            float4 v = *(const float4*)(rbuf + (size_t)(m0 + row) * DD + dc + seg * 4);
            lr[(seg * 4 + 0) * LRS + row] = v.x;
            lr[(seg * 4 + 1) * LRS + row] = v.y;
            lr[(seg * 4 + 2) * LRS + row] = v.z;
            lr[(seg * 4 + 3) * LRS + row] = v.w;
        }
        __syncthreads();

        #pragma unroll
        for (int g = 0; g < 2; ++g) {
            #pragma unroll
            for (int s = 0; s < 8; ++s) {
                const int kc = g * 8 + s;
                const float4* xp = (const float4*)&lx[kc * LXS + TB * ty];
                float4 xa = xp[0], xb = xp[1];
                const float4* rp = (const float4*)&lr[kc * LRS + TM * tx];
                float4 rv = rp[0];
                float xf[TB] = {xa.x, xa.y, xa.z, xa.w, xb.x, xb.y, xb.z, xb.w};
                float rf[TM] = {rv.x, rv.y, rv.z, rv.w};
                #pragma unroll
                for (int i = 0; i < TB; ++i)
                    #pragma unroll
                    for (int j = 0; j < TM; ++j)
                        prod[i][j] *= fmaf(xf[i], rf[j], 1.0f);
            }
            // close group of 8: exact exponent extraction, keep mantissa
            #pragma unroll
            for (int i = 0; i < TB; ++i)
                #pragma unroll
                for (int j = 0; j < TM; ++j) {
                    float p = prod[i][j];
                    acce[i][j] += fr_exp(p);
                    prod[i][j] = fr_mant(p);
                }
        }
    }

    #pragma unroll
    for (int i = 0; i < TB; ++i)
        #pragma unroll
        for (int j = 0; j < TM; ++j) {
            float v = (float)acce[i][j] + __log2f(prod[i][j]);
            int b = b0 + TB * ty + i;
            int m = m0 + TM * tx + j;
            atomicAdd(&comp2[(size_t)b * MM + m], v);
        }
}

// ---------------------------------------------------------------------------
// Kernel C: per-batch logsumexp over m (log2 domain), scale by ln2.
// One wave per batch, 4 batches per block.
// ---------------------------------------------------------------------------
__global__ __launch_bounds__(256) void finalize_kernel(
        const float* __restrict__ comp2, const float* __restrict__ cst,
        float* __restrict__ out) {
    const int lane = threadIdx.x & 63;
    const int w = threadIdx.x >> 6;
    const int b = blockIdx.x * 4 + w;

    const float* row = comp2 + (size_t)b * MM;
    float v0 = row[lane]       + cst[lane];
    float v1 = row[lane + 64]  + cst[lane + 64];
    float v2 = row[lane + 128] + cst[lane + 128];
    float v3 = row[lane + 192] + cst[lane + 192];

    float mx = fmaxf(fmaxf(v0, v1), fmaxf(v2, v3));
    #pragma unroll
    for (int o = 32; o; o >>= 1) mx = fmaxf(mx, __shfl_xor(mx, o));

    float s = exp2f(v0 - mx) + exp2f(v1 - mx) + exp2f(v2 - mx) + exp2f(v3 - mx);
    #pragma unroll
    for (int o = 32; o; o >>= 1) s += __shfl_xor(s, o);

    if (lane == 0) out[b] = LN2 * (mx + __log2f(s));
}

extern "C" void kernel_launch(void* const* d_in, const int* in_sizes, int n_in,
                              void* d_out, int out_size, void* d_ws, size_t ws_size,
                              hipStream_t stream) {
    const float* x  = (const float*)d_in[0];
    const float* Wv = (const float*)d_in[1];
    const float* P  = (const float*)d_in[2];
    float* ws    = (float*)d_ws;
    float* comp2 = ws + WS_COMP;
    float* rbuf  = ws + WS_R;
    float* cst   = ws + WS_CST;

    hipMemsetAsync(comp2, 0, (size_t)BATCH * MM * sizeof(float), stream);
    precomp_kernel<<<MM, 256, 0, stream>>>(P, Wv, rbuf, cst);
    dim3 gB(MM / BM, BATCH / BB, SD);
    main_kernel<<<gB, 256, 0, stream>>>(x, rbuf, comp2);
    finalize_kernel<<<BATCH / 4, 256, 0, stream>>>(comp2, cst, (float*)d_out);
}

// Round 2
// 106.256 us; speedup vs baseline: 1.7894x; 1.7894x over previous
//
#include <hip/hip_runtime.h>

// Problem constants (fixed by the reference file)
#define BATCH 2048
#define MM    256
#define DD    1024

// Main-kernel tiling
#define BB 128          // batches per block
#define BM 64           // mixture components per block
#define KC 16           // d per LDS stage
#define TB 8            // per-thread batch tile
#define TM 4            // per-thread m tile
#define LXS (BB + 4)    // padded LDS row stride (words); 132*4B % 16 == 0
#define LRS (BM + 4)    // 68*4B % 16 == 0

#define LOG2E 1.4426950408889634f
#define LN2   0.6931471805599453f

// ---- exact log2 bookkeeping via frexp (full-rate VALU, no transcendental) ----
__device__ __forceinline__ float fr_mant(float x) {
#if __has_builtin(__builtin_amdgcn_frexp_mantf)
    return __builtin_amdgcn_frexp_mantf(x);
#else
    unsigned u = __float_as_uint(x);
    return __uint_as_float((u & 0x807FFFFFu) | 0x3F000000u);  // mant in [0.5,1)
#endif
}
__device__ __forceinline__ int fr_exp(float x) {
#if __has_builtin(__builtin_amdgcn_frexp_expf)
    return __builtin_amdgcn_frexp_expf(x);
#else
    return (int)((__float_as_uint(x) >> 23) & 0xFFu) - 126;
#endif
}

// ---------------------------------------------------------------------------
// Kernel A: precompute r[m][d] = e^z - 1  (so lik = q*(1 + x*r), q = 1-p)
// and cst[m] = sum_d log2(q[m][d]) + log2(softmax(W)[m])
// ---------------------------------------------------------------------------
__global__ __launch_bounds__(256) void precomp_kernel(
        const float* __restrict__ P, const float* __restrict__ Wv,
        float* __restrict__ rbuf, float* __restrict__ cst) {
    const int m = blockIdx.x;
    const int t = threadIdx.x;
    const int lane = t & 63, wid = t >> 6;

    float4 z = ((const float4*)(P + (size_t)m * DD))[t];
    float e0 = __expf(z.x), e1 = __expf(z.y), e2 = __expf(z.z), e3 = __expf(z.w);
    ((float4*)(rbuf + (size_t)m * DD))[t] =
        make_float4(e0 - 1.f, e1 - 1.f, e2 - 1.f, e3 - 1.f);
    // log2(q) = -log2(1 + e^z)
    float part = -(__log2f(1.f + e0) + __log2f(1.f + e1) +
                   __log2f(1.f + e2) + __log2f(1.f + e3));

    __shared__ float smA[4], smB[4];

    #pragma unroll
    for (int o = 32; o; o >>= 1) part += __shfl_xor(part, o);
    if (lane == 0) smA[wid] = part;

    float w = Wv[t];   // blockDim == MM == 256
    float mx = w;
    #pragma unroll
    for (int o = 32; o; o >>= 1) mx = fmaxf(mx, __shfl_xor(mx, o));
    if (lane == 0) smB[wid] = mx;
    __syncthreads();

    float rowc = smA[0] + smA[1] + smA[2] + smA[3];
    float gmx  = fmaxf(fmaxf(smB[0], smB[1]), fmaxf(smB[2], smB[3]));

    float se = __expf(w - gmx);
    #pragma unroll
    for (int o = 32; o; o >>= 1) se += __shfl_xor(se, o);
    __syncthreads();
    if (lane == 0) smA[wid] = se;
    __syncthreads();

    if (t == 0) {
        float sum = smA[0] + smA[1] + smA[2] + smA[3];
        cst[m] = rowc + (Wv[m] - gmx) * LOG2E - __log2f(sum);
    }
}

// ---------------------------------------------------------------------------
// Kernel B: pbuf[sd][b][m] = sum_{d in split} log2(1 + x[b][d]*r[m][d])
// Register tile TB x TM per thread; products of 8 closed via frexp.
// Plain stores — NO atomics (round-1 lesson: atomic ping-pong cost 144 MB HBM).
// ---------------------------------------------------------------------------
__global__ __launch_bounds__(256, 4) void main_kernel(
        const float* __restrict__ x, const float* __restrict__ rbuf,
        float* __restrict__ pbuf, int dc) {   // dc = d-columns per block
    __shared__ __align__(16) float lx[KC * LXS];
    __shared__ __align__(16) float lr[KC * LRS];

    const int tid = threadIdx.x;
    const int tx = tid & 15;    // m direction (16 * TM = 64)
    const int ty = tid >> 4;    // batch direction (16 * TB = 128)
    const int m0 = blockIdx.x * BM;
    const int b0 = blockIdx.y * BB;
    const int d0 = blockIdx.z * dc;

    float prod[TB][TM];
    int   acce[TB][TM];
    #pragma unroll
    for (int i = 0; i < TB; ++i)
        #pragma unroll
        for (int j = 0; j < TM; ++j) { prod[i][j] = 1.0f; acce[i][j] = 0; }

    for (int c = 0; c < dc / KC; ++c) {
        const int d = d0 + c * KC;
        __syncthreads();
        // stage x tile [KC][BB] transposed: 128 rows x 4 float4-segs
        #pragma unroll
        for (int l = 0; l < 2; ++l) {
            int idx = tid + 256 * l;
            int row = idx >> 2;          // 0..127
            int seg = idx & 3;           // 0..3
            float4 v = *(const float4*)(x + (size_t)(b0 + row) * DD + d + seg * 4);
            lx[(seg * 4 + 0) * LXS + row] = v.x;
            lx[(seg * 4 + 1) * LXS + row] = v.y;
            lx[(seg * 4 + 2) * LXS + row] = v.z;
            lx[(seg * 4 + 3) * LXS + row] = v.w;
        }
        // stage r tile [KC][BM] transposed: 64 rows x 4 float4-segs
        {
            int row = tid >> 2;          // 0..63
            int seg = tid & 3;
            float4 v = *(const float4*)(rbuf + (size_t)(m0 + row) * DD + d + seg * 4);
            lr[(seg * 4 + 0) * LRS + row] = v.x;
            lr[(seg * 4 + 1) * LRS + row] = v.y;
            lr[(seg * 4 + 2) * LRS + row] = v.z;
            lr[(seg * 4 + 3) * LRS + row] = v.w;
        }
        __syncthreads();

        #pragma unroll
        for (int g = 0; g < 2; ++g) {
            #pragma unroll
            for (int s = 0; s < 8; ++s) {
                const int kc = g * 8 + s;
                const float4* xp = (const float4*)&lx[kc * LXS + TB * ty];
                float4 xa = xp[0], xb = xp[1];
                const float4* rp = (const float4*)&lr[kc * LRS + TM * tx];
                float4 rv = rp[0];
                float xf[TB] = {xa.x, xa.y, xa.z, xa.w, xb.x, xb.y, xb.z, xb.w};
                float rf[TM] = {rv.x, rv.y, rv.z, rv.w};
                #pragma unroll
                for (int i = 0; i < TB; ++i)
                    #pragma unroll
                    for (int j = 0; j < TM; ++j)
                        prod[i][j] *= fmaf(xf[i], rf[j], 1.0f);
            }
            // close group of 8: exact exponent extraction, keep mantissa
            #pragma unroll
            for (int i = 0; i < TB; ++i)
                #pragma unroll
                for (int j = 0; j < TM; ++j) {
                    float p = prod[i][j];
                    acce[i][j] += fr_exp(p);
                    prod[i][j] = fr_mant(p);
                }
        }
    }

    // Plain partial stores: pbuf[z][b][m]
    float* pb = pbuf + ((size_t)blockIdx.z * BATCH + b0) * MM + m0;
    #pragma unroll
    for (int i = 0; i < TB; ++i)
        #pragma unroll
        for (int j = 0; j < TM; ++j) {
            float v = (float)acce[i][j] + __log2f(prod[i][j]);
            pb[(size_t)(TB * ty + i) * MM + TM * tx + j] = v;
        }
}

// ---------------------------------------------------------------------------
// Kernel C: sum SD partials + cst, then per-batch logsumexp over m.
// One wave per batch, 4 batches per block.
// ---------------------------------------------------------------------------
__global__ __launch_bounds__(256) void finalize_kernel(
        const float* __restrict__ pbuf, const float* __restrict__ cst,
        float* __restrict__ out, int sd) {
    const int lane = threadIdx.x & 63;
    const int w = threadIdx.x >> 6;
    const int b = blockIdx.x * 4 + w;

    float v0 = cst[lane];
    float v1 = cst[lane + 64];
    float v2 = cst[lane + 128];
    float v3 = cst[lane + 192];

    for (int s = 0; s < sd; ++s) {
        const float* row = pbuf + ((size_t)s * BATCH + b) * MM;
        v0 += row[lane];
        v1 += row[lane + 64];
        v2 += row[lane + 128];
        v3 += row[lane + 192];
    }

    float mx = fmaxf(fmaxf(v0, v1), fmaxf(v2, v3));
    #pragma unroll
    for (int o = 32; o; o >>= 1) mx = fmaxf(mx, __shfl_xor(mx, o));

    float s = exp2f(v0 - mx) + exp2f(v1 - mx) + exp2f(v2 - mx) + exp2f(v3 - mx);
    #pragma unroll
    for (int o = 32; o; o >>= 1) s += __shfl_xor(s, o);

    if (lane == 0) out[b] = LN2 * (mx + __log2f(s));
}

extern "C" void kernel_launch(void* const* d_in, const int* in_sizes, int n_in,
                              void* d_out, int out_size, void* d_ws, size_t ws_size,
                              hipStream_t stream) {
    const float* x  = (const float*)d_in[0];
    const float* Wv = (const float*)d_in[1];
    const float* P  = (const float*)d_in[2];

    // ws layout (floats): [rbuf: MM*DD][cst: MM][pbuf: sd*BATCH*MM]
    float* ws   = (float*)d_ws;
    float* rbuf = ws;
    float* cst  = rbuf + (size_t)MM * DD;
    float* pbuf = cst + MM;

    // choose d-split count by available workspace for pbuf
    size_t fixed = ((size_t)MM * DD + MM) * sizeof(float);
    size_t avail = (ws_size > fixed) ? (ws_size - fixed) : 0;
    int sd = 16;
    while (sd > 1 && (size_t)sd * BATCH * MM * sizeof(float) > avail) sd >>= 1;

    precomp_kernel<<<MM, 256, 0, stream>>>(P, Wv, rbuf, cst);
    dim3 gB(MM / BM, BATCH / BB, sd);
    main_kernel<<<gB, 256, 0, stream>>>(x, rbuf, pbuf, DD / sd);
    finalize_kernel<<<BATCH / 4, 256, 0, stream>>>(pbuf, cst, (float*)d_out, sd);
}

// Round 3
// 105.841 us; speedup vs baseline: 1.7964x; 1.0039x over previous
//
#include <hip/hip_runtime.h>

// Problem constants (fixed by the reference file)
#define BATCH 2048
#define MM    256
#define DD    1024

// Main-kernel tiling
#define BB 128          // batches per block
#define BM 64           // mixture components per block
#define KC 16           // d per LDS stage
#define TB 8            // per-thread batch tile
#define TM 4            // per-thread m tile
#define LXS (BB + 4)    // padded LDS row stride (words) — conflict-free frag reads
#define LRS (BM + 4)
#define NBT (BATCH / BB)   // 16 b-tiles

#define LOG2E 1.4426950408889634f
#define LN2   0.6931471805599453f

// ---- exact log2 bookkeeping via frexp (full-rate VALU, no transcendental) ----
__device__ __forceinline__ float fr_mant(float x) {
#if __has_builtin(__builtin_amdgcn_frexp_mantf)
    return __builtin_amdgcn_frexp_mantf(x);
#else
    unsigned u = __float_as_uint(x);
    return __uint_as_float((u & 0x807FFFFFu) | 0x3F000000u);
#endif
}
__device__ __forceinline__ int fr_exp(float x) {
#if __has_builtin(__builtin_amdgcn_frexp_expf)
    return __builtin_amdgcn_frexp_expf(x);
#else
    return (int)((__float_as_uint(x) >> 23) & 0xFFu) - 126;
#endif
}

// ---------------------------------------------------------------------------
// Kernel A: r[m][d] = e^z - 1  (lik = q*(1 + x*r), q = 1-p)
// cst[m] = sum_d log2 q[m][d] + log2 softmax(W)[m]
// ---------------------------------------------------------------------------
__global__ __launch_bounds__(256) void precomp_kernel(
        const float* __restrict__ P, const float* __restrict__ Wv,
        float* __restrict__ rbuf, float* __restrict__ cst) {
    const int m = blockIdx.x;
    const int t = threadIdx.x;
    const int lane = t & 63, wid = t >> 6;

    float4 z = ((const float4*)(P + (size_t)m * DD))[t];
    float e0 = __expf(z.x), e1 = __expf(z.y), e2 = __expf(z.z), e3 = __expf(z.w);
    ((float4*)(rbuf + (size_t)m * DD))[t] =
        make_float4(e0 - 1.f, e1 - 1.f, e2 - 1.f, e3 - 1.f);
    float part = -(__log2f(1.f + e0) + __log2f(1.f + e1) +
                   __log2f(1.f + e2) + __log2f(1.f + e3));

    __shared__ float smA[4], smB[4];

    #pragma unroll
    for (int o = 32; o; o >>= 1) part += __shfl_xor(part, o);
    if (lane == 0) smA[wid] = part;

    float w = Wv[t];
    float mx = w;
    #pragma unroll
    for (int o = 32; o; o >>= 1) mx = fmaxf(mx, __shfl_xor(mx, o));
    if (lane == 0) smB[wid] = mx;
    __syncthreads();

    float rowc = smA[0] + smA[1] + smA[2] + smA[3];
    float gmx  = fmaxf(fmaxf(smB[0], smB[1]), fmaxf(smB[2], smB[3]));

    float se = __expf(w - gmx);
    #pragma unroll
    for (int o = 32; o; o >>= 1) se += __shfl_xor(se, o);
    __syncthreads();
    if (lane == 0) smA[wid] = se;
    __syncthreads();

    if (t == 0) {
        float sum = smA[0] + smA[1] + smA[2] + smA[3];
        cst[m] = rowc + (Wv[m] - gmx) * LOG2E - __log2f(sum);
    }
}

// ---------------------------------------------------------------------------
// Kernel B: pbuf[d_id][b][m] = sum_{d in split} log2(1 + x[b][d]*r[m][d])
// Register-prefetch pipelined staging; XCD-swizzled 1-D grid so the 4
// m-blocks sharing an x-tile run consecutively on one XCD (L2 reuse).
// ---------------------------------------------------------------------------
__global__ __launch_bounds__(256, 4) void main_kernel(
        const float* __restrict__ x, const float* __restrict__ rbuf,
        float* __restrict__ pbuf, int dc) {
    __shared__ __align__(16) float lx[KC * LXS];
    __shared__ __align__(16) float lr[KC * LRS];

    const int tid = threadIdx.x;
    const int tx = tid & 15;    // m direction (16 * TM = 64)
    const int ty = tid >> 4;    // batch direction (16 * TB = 128)

    // XCD-swizzled decode. blocks = NBT*sd*4; gid -> (xcd, k); 4 consecutive
    // k on one XCD share one (b,d) tile (different m) -> x-tile L2 reuse.
    const int gid  = blockIdx.x;
    const int xcd  = gid & 7;
    const int k    = gid >> 3;
    const int m_id = k & 3;
    const int tile = (k >> 2) * 8 + xcd;
    const int b_id = tile & (NBT - 1);
    const int d_id = tile / NBT;

    const int m0 = m_id * BM;
    const int b0 = b_id * BB;
    const int d0 = d_id * dc;
    const int NC = dc / KC;

    // staging source pointers (advance by KC per stage); all 16B-aligned
    const int rowx = tid >> 2, segx = tid & 3;
    const float* xp0 = x + (size_t)(b0 + rowx) * DD + d0 + segx * 4;
    const float* xp1 = xp0 + (size_t)64 * DD;
    const float* rp  = rbuf + (size_t)(m0 + rowx) * DD + d0 + segx * 4;

    float4 cx0 = *(const float4*)xp0;
    float4 cx1 = *(const float4*)xp1;
    float4 cr  = *(const float4*)rp;

    float prod[TB][TM];
    int   acce[TB][TM];
    #pragma unroll
    for (int i = 0; i < TB; ++i)
        #pragma unroll
        for (int j = 0; j < TM; ++j) { prod[i][j] = 1.0f; acce[i][j] = 0; }

    for (int c = 0; c < NC; ++c) {
        __syncthreads();
        // commit current staging registers to LDS (transposed, padded)
        {
            const int base = segx * 4;
            lx[(base + 0) * LXS + rowx] = cx0.x;
            lx[(base + 1) * LXS + rowx] = cx0.y;
            lx[(base + 2) * LXS + rowx] = cx0.z;
            lx[(base + 3) * LXS + rowx] = cx0.w;
            lx[(base + 0) * LXS + rowx + 64] = cx1.x;
            lx[(base + 1) * LXS + rowx + 64] = cx1.y;
            lx[(base + 2) * LXS + rowx + 64] = cx1.z;
            lx[(base + 3) * LXS + rowx + 64] = cx1.w;
            if (rowx < BM) {
                lr[(base + 0) * LRS + rowx] = cr.x;
                lr[(base + 1) * LRS + rowx] = cr.y;
                lr[(base + 2) * LRS + rowx] = cr.z;
                lr[(base + 3) * LRS + rowx] = cr.w;
            }
        }
        // prefetch next stage into registers (hides HBM latency behind compute)
        if (c + 1 < NC) {
            xp0 += KC; xp1 += KC; rp += KC;
            cx0 = *(const float4*)xp0;
            cx1 = *(const float4*)xp1;
            cr  = *(const float4*)rp;
        }
        __syncthreads();

        #pragma unroll
        for (int g = 0; g < 2; ++g) {
            #pragma unroll
            for (int s = 0; s < 8; ++s) {
                const int kc = g * 8 + s;
                const float4* xp = (const float4*)&lx[kc * LXS + TB * ty];
                float4 xa = xp[0], xb = xp[1];
                const float4* rpf = (const float4*)&lr[kc * LRS + TM * tx];
                float4 rv = rpf[0];
                float xf[TB] = {xa.x, xa.y, xa.z, xa.w, xb.x, xb.y, xb.z, xb.w};
                float rf[TM] = {rv.x, rv.y, rv.z, rv.w};
                #pragma unroll
                for (int i = 0; i < TB; ++i)
                    #pragma unroll
                    for (int j = 0; j < TM; ++j)
                        prod[i][j] *= fmaf(xf[i], rf[j], 1.0f);
            }
            // close group of 8 d: exact exponent extraction (range-safe:
            // t in [0.004, ~250] -> 8-products within fp32 normal range)
            #pragma unroll
            for (int i = 0; i < TB; ++i)
                #pragma unroll
                for (int j = 0; j < TM; ++j) {
                    float p = prod[i][j];
                    acce[i][j] += fr_exp(p);
                    prod[i][j] = fr_mant(p);
                }
        }
    }

    // coalesced float4 stores: pbuf[d_id][b][m]
    float* pb = pbuf + ((size_t)d_id * BATCH + b0) * MM + m0;
    #pragma unroll
    for (int i = 0; i < TB; ++i) {
        float4 vv;
        vv.x = (float)acce[i][0] + __log2f(prod[i][0]);
        vv.y = (float)acce[i][1] + __log2f(prod[i][1]);
        vv.z = (float)acce[i][2] + __log2f(prod[i][2]);
        vv.w = (float)acce[i][3] + __log2f(prod[i][3]);
        *(float4*)&pb[(size_t)(TB * ty + i) * MM + TM * tx] = vv;
    }
}

// ---------------------------------------------------------------------------
// Kernel C (sd=16 fast path): one wave per batch, lane covers 4 m's (float4).
// 16 fully-unrolled independent dwordx4 loads -> MLP-saturated.
// ---------------------------------------------------------------------------
__global__ __launch_bounds__(256) void finalize16_kernel(
        const float4* __restrict__ pbuf4, const float4* __restrict__ cst4,
        float* __restrict__ out) {
    const int lane = threadIdx.x & 63;
    const int w = threadIdx.x >> 6;
    const int b = blockIdx.x * 4 + w;

    float4 v = cst4[lane];
    const float4* pb = pbuf4 + (size_t)b * (MM / 4) + lane;
    #pragma unroll
    for (int s = 0; s < 16; ++s) {
        float4 t = pb[(size_t)s * BATCH * (MM / 4)];
        v.x += t.x; v.y += t.y; v.z += t.z; v.w += t.w;
    }

    float mx = fmaxf(fmaxf(v.x, v.y), fmaxf(v.z, v.w));
    #pragma unroll
    for (int o = 32; o; o >>= 1) mx = fmaxf(mx, __shfl_xor(mx, o));

    float s = exp2f(v.x - mx) + exp2f(v.y - mx) + exp2f(v.z - mx) + exp2f(v.w - mx);
    #pragma unroll
    for (int o = 32; o; o >>= 1) s += __shfl_xor(s, o);

    if (lane == 0) out[b] = LN2 * (mx + __log2f(s));
}

// Generic fallback (sd != 16)
__global__ __launch_bounds__(256) void finalize_kernel(
        const float* __restrict__ pbuf, const float* __restrict__ cst,
        float* __restrict__ out, int sd) {
    const int lane = threadIdx.x & 63;
    const int w = threadIdx.x >> 6;
    const int b = blockIdx.x * 4 + w;

    float v0 = cst[lane];
    float v1 = cst[lane + 64];
    float v2 = cst[lane + 128];
    float v3 = cst[lane + 192];

    for (int s = 0; s < sd; ++s) {
        const float* row = pbuf + ((size_t)s * BATCH + b) * MM;
        v0 += row[lane];
        v1 += row[lane + 64];
        v2 += row[lane + 128];
        v3 += row[lane + 192];
    }

    float mx = fmaxf(fmaxf(v0, v1), fmaxf(v2, v3));
    #pragma unroll
    for (int o = 32; o; o >>= 1) mx = fmaxf(mx, __shfl_xor(mx, o));

    float s = exp2f(v0 - mx) + exp2f(v1 - mx) + exp2f(v2 - mx) + exp2f(v3 - mx);
    #pragma unroll
    for (int o = 32; o; o >>= 1) s += __shfl_xor(s, o);

    if (lane == 0) out[b] = LN2 * (mx + __log2f(s));
}

extern "C" void kernel_launch(void* const* d_in, const int* in_sizes, int n_in,
                              void* d_out, int out_size, void* d_ws, size_t ws_size,
                              hipStream_t stream) {
    const float* x  = (const float*)d_in[0];
    const float* Wv = (const float*)d_in[1];
    const float* P  = (const float*)d_in[2];

    // ws layout (floats): [rbuf: MM*DD][cst: MM][pbuf: sd*BATCH*MM]
    float* ws   = (float*)d_ws;
    float* rbuf = ws;
    float* cst  = rbuf + (size_t)MM * DD;
    float* pbuf = cst + MM;

    size_t fixed = ((size_t)MM * DD + MM) * sizeof(float);
    size_t avail = (ws_size > fixed) ? (ws_size - fixed) : 0;
    int sd = 16;
    while (sd > 1 && (size_t)sd * BATCH * MM * sizeof(float) > avail) sd >>= 1;

    precomp_kernel<<<MM, 256, 0, stream>>>(P, Wv, rbuf, cst);
    int nblocks = NBT * sd * 4;   // 1-D swizzled grid
    main_kernel<<<nblocks, 256, 0, stream>>>(x, rbuf, pbuf, DD / sd);
    if (sd == 16)
        finalize16_kernel<<<BATCH / 4, 256, 0, stream>>>(
            (const float4*)pbuf, (const float4*)cst, (float*)d_out);
    else
        finalize_kernel<<<BATCH / 4, 256, 0, stream>>>(pbuf, cst, (float*)d_out, sd);
}